// Round 18
// baseline (428.131 us; speedup 1.0000x reference)
//
#include <hip/hip_runtime.h>
#include <hip/hip_bf16.h>

#define B_TOK 2048
#define DDIM 1024
#define NEXP 32
#define HDIM 1024
#define TOPK 8
#define PITCH 1088  // bf16 row pitch = 2176 B = 17*128
#define BM 192

typedef __bf16 bf16_t;
typedef __bf16 bf16x8 __attribute__((ext_vector_type(8)));
typedef float f32x4 __attribute__((ext_vector_type(4)));

// ---------------- xb = bf16(x) [pitched] ----------------
__global__ __launch_bounds__(256) void k_prep(const float* __restrict__ x,
                                              bf16_t* __restrict__ xb) {
  int i = (blockIdx.x * 256 + threadIdx.x) * 8;
  float4 v0 = *(const float4*)&x[i];
  float4 v1 = *(const float4*)&x[i + 4];
  bf16x8 v;
  v[0] = (bf16_t)v0.x; v[1] = (bf16_t)v0.y; v[2] = (bf16_t)v0.z; v[3] = (bf16_t)v0.w;
  v[4] = (bf16_t)v1.x; v[5] = (bf16_t)v1.y; v[6] = (bf16_t)v1.z; v[7] = (bf16_t)v1.w;
  int row = i >> 10, col = i & 1023;
  *(bf16x8*)&xb[(size_t)row * PITCH + col] = v;
}

// ---------------- gating: softmax + top-8 ----------------
__global__ __launch_bounds__(256) void k_gating(const float* __restrict__ x,
                                                const float* __restrict__ Wg,
                                                int* __restrict__ sel_e,
                                                float* __restrict__ sel_w) {
  int token = blockIdx.x * 4 + (threadIdx.x >> 6);
  int lane = threadIdx.x & 63;
  int e = lane & 31;
  int half = lane >> 5;
  const float* xr = x + (size_t)token * DDIM + half * (DDIM / 2);
  const float* wg = Wg + (size_t)half * (DDIM / 2) * NEXP + e;
  float acc = 0.f;
#pragma unroll 8
  for (int k = 0; k < DDIM / 2; ++k) acc = fmaf(xr[k], wg[k * NEXP], acc);
  acc += __shfl_xor(acc, 32);
  float m = acc;
  for (int off = 16; off; off >>= 1) m = fmaxf(m, __shfl_xor(m, off));
  float p = __expf(acc - m);
  float s = p;
  for (int off = 16; off; off >>= 1) s += __shfl_xor(s, off);
  p /= s;
  float pv = p;
  int my_se = 0;
  float my_sw = 0.f;
  for (int it = 0; it < TOPK; ++it) {
    float mx = pv;
    for (int off = 16; off; off >>= 1) mx = fmaxf(mx, __shfl_xor(mx, off));
    unsigned long long bal = __ballot(pv == mx);
    int sl = __ffsll(bal) - 1;
    int se = sl & 31;
    if (lane == it) { my_se = se; my_sw = mx; }
    if (e == se) pv = -1.f;
  }
  if (lane < TOPK) {
    sel_e[token * TOPK + lane] = my_se;
    sel_w[token * TOPK + lane] = my_sw;
  }
}

// ---------------- deterministic per-expert compaction ----------------
__global__ __launch_bounds__(256) void k_build_lists(const int* __restrict__ sel_e,
                                                     const float* __restrict__ sel_w,
                                                     int* __restrict__ list,
                                                     float* __restrict__ wlist,
                                                     int* __restrict__ count) {
  int e = blockIdx.x;
  int t = threadIdx.x;
  int lane = t & 63, wv = t >> 6;
  __shared__ int wsum[4];
  __shared__ int base;
  if (t == 0) base = 0;
  __syncthreads();
  for (int c = 0; c < B_TOK; c += 256) {
    int b = c + t;
    int flag = 0, slot = 0;
    float w = 0.f;
#pragma unroll
    for (int j = 0; j < TOPK; ++j) {
      if (sel_e[b * TOPK + j] == e) { flag = 1; slot = j; w = sel_w[b * TOPK + j]; }
    }
    unsigned long long bal = __ballot(flag);
    int pre = __popcll(bal & ((1ull << lane) - 1ull));
    int tot = __popcll(bal);
    if (lane == 0) wsum[wv] = tot;
    __syncthreads();
    int off = base;
    for (int i = 0; i < wv; ++i) off += wsum[i];
    if (flag) {
      int pos = off + pre;
      list[e * B_TOK + pos] = (b << 3) | slot;
      wlist[e * B_TOK + pos] = w;
    }
    __syncthreads();
    if (t == 0) base += wsum[0] + wsum[1] + wsum[2] + wsum[3];
    __syncthreads();
  }
  if (t == 0) count[e] = base;
}

// --------- compact balanced work queue: BM=192, y 0..7 (BN=128) -----------
__global__ __launch_bounds__(64) void k_build_queue(const int* __restrict__ count,
                                                    int* __restrict__ queue,
                                                    int* __restrict__ qn) {
  int e = threadIdx.x;
  int nmt = 0;
  if (e < NEXP) nmt = (count[e] + BM - 1) / BM;
  int pref = 0, tot = 0;
  for (int i = 0; i < NEXP; ++i) {
    int v = __shfl(nmt, i);
    if (i < e) pref += v;
    tot += v;
  }
  if (e < NEXP) {
    int base = pref * 8;
    for (int y = 0; y < 8; ++y)
      for (int mt = 0; mt < nmt; ++mt)
        queue[base + y * nmt + mt] = (e << 8) | (mt << 3) | y;
  }
  if (threadIdx.x == 0) qn[0] = tot * 8;
}

// ---------------- final: out = x + sum_slots ybuf ----------------
__global__ __launch_bounds__(256) void k_reduce(const float* __restrict__ x,
                                               const float* __restrict__ ybuf,
                                               float* __restrict__ out) {
  int i = (blockIdx.x * 256 + threadIdx.x) * 4;
  int tok = i >> 10;
  int d = i & 1023;
  float4 s = *(const float4*)&x[i];
  const float* yb = ybuf + (size_t)tok * 8 * 1024 + d;
#pragma unroll
  for (int sl = 0; sl < 8; ++sl) {
    float4 v = *(const float4*)&yb[sl * 1024];
    s.x += v.x; s.y += v.y; s.z += v.z; s.w += v.w;
  }
  *(float4*)&out[i] = s;
}

// ====== grouped GEMM: BM=192, fused B cvt+transpose (R16 loop) =============
__device__ __forceinline__ void async_load16(const bf16_t* g, bf16_t* l) {
  __builtin_amdgcn_global_load_lds((const __attribute__((address_space(1))) void*)g,
                                   (__attribute__((address_space(3))) void*)l, 16, 0, 0);
}

#define LOADB(LO, HI, KT)                                                     \
  {                                                                           \
    const float* p_ = bcol + (size_t)((KT)*64 + aB * 8) * 1024;               \
    _Pragma("unroll") for (int kk = 0; kk < 8; ++kk) {                        \
      LO[kk] = *(const float2*)(p_ + (size_t)kk * 1024);                      \
      HI[kk] = *(const float2*)(p_ + (size_t)kk * 1024 + 64);                 \
    }                                                                         \
  }

#define CVTWRITE(LO, HI)                                                      \
  {                                                                           \
    _Pragma("unroll") for (int jn = 0; jn < 4; ++jn) {                        \
      const int n = (jn < 2) ? (2 * qB + jn) : (64 + 2 * qB + (jn - 2));      \
      bf16x8 pk;                                                              \
      _Pragma("unroll") for (int kk = 0; kk < 8; ++kk)                        \
          pk[kk] = (bf16_t)((jn == 0) ? LO[kk].x : (jn == 1) ? LO[kk].y       \
                            : (jn == 2) ? HI[kk].x : HI[kk].y);               \
      *(bf16x8*)&Bs[n][(aB ^ (n & 7)) << 3] = pk;                             \
    }                                                                         \
  }

#define ISSUE_A(KT)                                                           \
  {                                                                           \
    _Pragma("unroll") for (int i = 0; i < 6; ++i)                             \
        async_load16(aptr[i] + (KT)*64, &As[w * 48 + i * 8][0]);              \
  }

#define MFMA_PHASE()                                                          \
  {                                                                           \
    bf16x8 af[6][2], bfr[4][2];                                               \
    _Pragma("unroll") for (int ks = 0; ks < 2; ++ks) {                        \
      const int ca = (((ks << 2) | hi) ^ l7) << 3;                            \
      _Pragma("unroll") for (int m = 0; m < 6; ++m)                           \
          af[m][ks] = *(const bf16x8*)&As[wm + m * 16 + lr][ca];              \
      _Pragma("unroll") for (int n = 0; n < 4; ++n)                           \
          bfr[n][ks] = *(const bf16x8*)&Bs[wc + n * 16 + lr][ca];             \
    }                                                                         \
    _Pragma("unroll") for (int m = 0; m < 6; ++m)                             \
        _Pragma("unroll") for (int n = 0; n < 4; ++n)                         \
            _Pragma("unroll") for (int ks = 0; ks < 2; ++ks)                  \
                acc[m][n] = __builtin_amdgcn_mfma_f32_16x16x32_bf16(          \
                    af[m][ks], bfr[n][ks], acc[m][n], 0, 0, 0);               \
  }

template <int PHASE>
__global__ __launch_bounds__(256, 3) void k_gemm(const bf16_t* __restrict__ Abase,
                                                 const float* __restrict__ Wraw,
                                                 const int* __restrict__ list,
                                                 const float* __restrict__ wlist,
                                                 const int* __restrict__ count,
                                                 const int* __restrict__ queue,
                                                 const int* __restrict__ qn,
                                                 const float* __restrict__ bias,
                                                 bf16_t* __restrict__ hbuf,
                                                 float* __restrict__ ybuf) {
  __shared__ bf16_t As[BM][64];   // 24 KB
  __shared__ bf16_t Bs[128][64];  // 16 KB

  const int phys = blockIdx.x;
  const int nwg = qn[0];
  if (phys >= nwg) return;
  // bijective XCD chunk transform (m204)
  const int q8 = nwg >> 3, r8 = nwg & 7;
  const int xcd = phys & 7, loc = phys >> 3;
  const int wk = (xcd < r8 ? xcd * (q8 + 1) : r8 * (q8 + 1) + (xcd - r8) * q8) + loc;

  const int ent = queue[wk];
  const int e = ent >> 8;
  const int mt = (ent >> 3) & 31;
  const int y = ent & 7;

  const int cnt = count[e];
  const int m0 = mt * BM;
  const int n0 = y * 128;

  const int t = threadIdx.x;
  const int lane = t & 63;
  const int w = t >> 6;          // 0..3
  const int wm = (w >> 1) * 96;  // 2 M-waves x 96 rows
  const int wc = (w & 1) << 6;   // 2 N-waves x 64 cols
  const int lr = lane & 15;
  const int hi = lane >> 4;      // 0..3
  const int l7 = lane & 7;
  const int srs = ((lane & 7) ^ (lane >> 3)) << 3;  // A pre-swizzled src slot

  const int* lrow = list + e * B_TOK;

  // A staging sources (192 rows, 6 per thread via global_load_lds)
  const bf16_t* aptr[6];
#pragma unroll
  for (int i = 0; i < 6; ++i) {
    int mi = m0 + w * 48 + i * 8 + (lane >> 3);
    if (mi > cnt - 1) mi = cnt - 1;
    int li = lrow[mi];
    int tok = li >> 3, slot = li & 7;
    size_t arow = (PHASE == 1) ? (size_t)tok * PITCH : ((size_t)tok * 8 + slot) * PITCH;
    aptr[i] = Abase + arow + srs;
  }

  // B staging thread mapping
  const int qB = t & 31;
  const int aB = t >> 5;
  const float* bcol = Wraw + (size_t)e * DDIM * HDIM + n0 + 2 * qB;

  f32x4 acc[6][4] = {};
  float2 valo[8], vahi[8], vblo[8], vbhi[8];

  // prologue: B(0) into va
  LOADB(valo, vahi, 0)

#pragma unroll 1
  for (int kt2 = 0; kt2 < 8; ++kt2) {
    const int ktA = kt2 * 2;
    const int ktB = ktA + 1;
    // ---- even kt: consume va, prefetch into vb ----
    ISSUE_A(ktA)
    CVTWRITE(valo, vahi)
    __syncthreads();           // A(ktA) in LDS, B(ktA) written
    LOADB(vblo, vbhi, ktB)     // in flight during MFMA
    MFMA_PHASE()
    __syncthreads();
    // ---- odd kt: consume vb, prefetch into va ----
    ISSUE_A(ktB)
    CVTWRITE(vblo, vbhi)
    __syncthreads();
    if (ktB < 15) LOADB(valo, vahi, ktB + 1)
    MFMA_PHASE()
    __syncthreads();
  }

  // Epilogue
  float biasv[4];
#pragma unroll
  for (int n = 0; n < 4; ++n) biasv[n] = bias[e * 1024 + n0 + wc + n * 16 + lr];

#pragma unroll
  for (int m = 0; m < 6; ++m) {
#pragma unroll
    for (int j = 0; j < 4; ++j) {
      int gm = m0 + wm + m * 16 + hi * 4 + j;
      if (gm < cnt) {
        int li2 = lrow[gm];
        int tok2 = li2 >> 3, slot2 = li2 & 7;
        if (PHASE == 1) {
          bf16_t* hr = hbuf + ((size_t)tok2 * 8 + slot2) * PITCH + n0 + wc + lr;
#pragma unroll
          for (int n = 0; n < 4; ++n) {
            float v = acc[m][n][j] + biasv[n];
            hr[n * 16] = (bf16_t)(v > 0.f ? v : 0.f);
          }
        } else {
          float gw = wlist[e * B_TOK + gm];
          float* yrow = ybuf + ((size_t)tok2 * 8 + slot2) * 1024 + n0 + wc + lr;
#pragma unroll
          for (int n = 0; n < 4; ++n) {
            yrow[n * 16] = (acc[m][n][j] + biasv[n]) * gw;  // plain store
          }
        }
      }
    }
  }
}

extern "C" void kernel_launch(void* const* d_in, const int* in_sizes, int n_in,
                              void* d_out, int out_size, void* d_ws, size_t ws_size,
                              hipStream_t stream) {
  const float* x = (const float*)d_in[0];
  const float* Wg = (const float*)d_in[1];
  const float* W1 = (const float*)d_in[2];
  const float* b1 = (const float*)d_in[3];
  const float* W2 = (const float*)d_in[4];
  const float* b2 = (const float*)d_in[5];
  float* out = (float*)d_out;

  char* ws = (char*)d_ws;
  bf16_t* xb = (bf16_t*)ws;   ws += (size_t)B_TOK * PITCH * 2;
  bf16_t* hbuf = (bf16_t*)ws; ws += (size_t)B_TOK * TOPK * PITCH * 2;
  float* ybuf = (float*)ws;   ws += (size_t)B_TOK * TOPK * 1024 * 4;
  int* sel_e = (int*)ws;      ws += (size_t)B_TOK * TOPK * 4;
  float* sel_w = (float*)ws;  ws += (size_t)B_TOK * TOPK * 4;
  int* list = (int*)ws;       ws += (size_t)NEXP * B_TOK * 4;
  float* wlist = (float*)ws;  ws += (size_t)NEXP * B_TOK * 4;
  int* count = (int*)ws;      ws += 64 * 4;
  int* queue = (int*)ws;      ws += 2048 * 4;
  int* qn = (int*)ws;         ws += 64 * 4;

  k_prep<<<1024, 256, 0, stream>>>(x, xb);
  k_gating<<<512, 256, 0, stream>>>(x, Wg, sel_e, sel_w);
  k_build_lists<<<32, 256, 0, stream>>>(sel_e, sel_w, list, wlist, count);
  k_build_queue<<<1, 64, 0, stream>>>(count, queue, qn);
  k_gemm<1><<<1536, 256, 0, stream>>>(xb, W1, list, wlist, count, queue, qn, b1, hbuf, ybuf);
  k_gemm<2><<<1536, 256, 0, stream>>>(hbuf, W2, list, wlist, count, queue, qn, b2, hbuf, ybuf);
  k_reduce<<<2048, 256, 0, stream>>>(x, ybuf, out);
}

// Round 19
// 255.297 us; speedup vs baseline: 1.6770x; 1.6770x over previous
//
#include <hip/hip_runtime.h>
#include <hip/hip_bf16.h>

#define B_TOK 2048
#define DDIM 1024
#define NEXP 32
#define HDIM 1024
#define TOPK 8
#define PITCH 1088  // bf16 row pitch = 2176 B = 17*128

typedef __bf16 bf16_t;
typedef __bf16 bf16x8 __attribute__((ext_vector_type(8)));
typedef float f32x4 __attribute__((ext_vector_type(4)));

// ---------------- fused: xb = bf16(x) [pitched]; out = x ----------------
__global__ __launch_bounds__(256) void k_prep(const float* __restrict__ x,
                                              bf16_t* __restrict__ xb,
                                              float* __restrict__ out) {
  int i = (blockIdx.x * 256 + threadIdx.x) * 8;
  float4 v0 = *(const float4*)&x[i];
  float4 v1 = *(const float4*)&x[i + 4];
  bf16x8 v;
  v[0] = (bf16_t)v0.x; v[1] = (bf16_t)v0.y; v[2] = (bf16_t)v0.z; v[3] = (bf16_t)v0.w;
  v[4] = (bf16_t)v1.x; v[5] = (bf16_t)v1.y; v[6] = (bf16_t)v1.z; v[7] = (bf16_t)v1.w;
  int row = i >> 10, col = i & 1023;
  *(bf16x8*)&xb[(size_t)row * PITCH + col] = v;
  *(float4*)&out[i] = v0;
  *(float4*)&out[i + 4] = v1;
}

// ---------------- gating: softmax + top-8 ----------------
__global__ __launch_bounds__(256) void k_gating(const float* __restrict__ x,
                                                const float* __restrict__ Wg,
                                                int* __restrict__ sel_e,
                                                float* __restrict__ sel_w) {
  int token = blockIdx.x * 4 + (threadIdx.x >> 6);
  int lane = threadIdx.x & 63;
  int e = lane & 31;
  int half = lane >> 5;
  const float* xr = x + (size_t)token * DDIM + half * (DDIM / 2);
  const float* wg = Wg + (size_t)half * (DDIM / 2) * NEXP + e;
  float acc = 0.f;
#pragma unroll 8
  for (int k = 0; k < DDIM / 2; ++k) acc = fmaf(xr[k], wg[k * NEXP], acc);
  acc += __shfl_xor(acc, 32);
  float m = acc;
  for (int off = 16; off; off >>= 1) m = fmaxf(m, __shfl_xor(m, off));
  float p = __expf(acc - m);
  float s = p;
  for (int off = 16; off; off >>= 1) s += __shfl_xor(s, off);
  p /= s;
  float pv = p;
  int my_se = 0;
  float my_sw = 0.f;
  for (int it = 0; it < TOPK; ++it) {
    float mx = pv;
    for (int off = 16; off; off >>= 1) mx = fmaxf(mx, __shfl_xor(mx, off));
    unsigned long long bal = __ballot(pv == mx);
    int sl = __ffsll(bal) - 1;
    int se = sl & 31;
    if (lane == it) { my_se = se; my_sw = mx; }
    if (e == se) pv = -1.f;
  }
  if (lane < TOPK) {
    sel_e[token * TOPK + lane] = my_se;
    sel_w[token * TOPK + lane] = my_sw;
  }
}

// ---------------- deterministic per-expert compaction ----------------
__global__ __launch_bounds__(256) void k_build_lists(const int* __restrict__ sel_e,
                                                     const float* __restrict__ sel_w,
                                                     int* __restrict__ list,
                                                     float* __restrict__ wlist,
                                                     int* __restrict__ count) {
  int e = blockIdx.x;
  int t = threadIdx.x;
  int lane = t & 63, wv = t >> 6;
  __shared__ int wsum[4];
  __shared__ int base;
  if (t == 0) base = 0;
  __syncthreads();
  for (int c = 0; c < B_TOK; c += 256) {
    int b = c + t;
    int flag = 0, slot = 0;
    float w = 0.f;
#pragma unroll
    for (int j = 0; j < TOPK; ++j) {
      if (sel_e[b * TOPK + j] == e) { flag = 1; slot = j; w = sel_w[b * TOPK + j]; }
    }
    unsigned long long bal = __ballot(flag);
    int pre = __popcll(bal & ((1ull << lane) - 1ull));
    int tot = __popcll(bal);
    if (lane == 0) wsum[wv] = tot;
    __syncthreads();
    int off = base;
    for (int i = 0; i < wv; ++i) off += wsum[i];
    if (flag) {
      int pos = off + pre;
      list[e * B_TOK + pos] = (b << 3) | slot;
      wlist[e * B_TOK + pos] = w;
    }
    __syncthreads();
    if (t == 0) base += wsum[0] + wsum[1] + wsum[2] + wsum[3];
    __syncthreads();
  }
  if (t == 0) count[e] = base;
}

// --------- compact balanced work queue: BM=128, y 0..7 (BN=128) -----------
__global__ __launch_bounds__(64) void k_build_queue(const int* __restrict__ count,
                                                    int* __restrict__ queue,
                                                    int* __restrict__ qn) {
  int e = threadIdx.x;
  int nmt = 0;
  if (e < NEXP) nmt = (count[e] + 127) >> 7;
  int pref = 0, tot = 0;
  for (int i = 0; i < NEXP; ++i) {
    int v = __shfl(nmt, i);
    if (i < e) pref += v;
    tot += v;
  }
  if (e < NEXP) {
    int base = pref * 8;
    for (int y = 0; y < 8; ++y)
      for (int mt = 0; mt < nmt; ++mt)
        queue[base + y * nmt + mt] = (e << 8) | (mt << 3) | y;
  }
  if (threadIdx.x == 0) qn[0] = tot * 8;
}

// ====== grouped GEMM with FUSED B transpose+convert + B-prefetch ===========
__device__ __forceinline__ void async_load16(const bf16_t* g, bf16_t* l) {
  __builtin_amdgcn_global_load_lds((const __attribute__((address_space(1))) void*)g,
                                   (__attribute__((address_space(3))) void*)l, 16, 0, 0);
}

#define LOADB(LO, HI, KT)                                                     \
  {                                                                           \
    const float* p_ = bcol + (size_t)((KT)*64 + aB * 8) * 1024;               \
    _Pragma("unroll") for (int kk = 0; kk < 8; ++kk) {                        \
      LO[kk] = *(const float2*)(p_ + (size_t)kk * 1024);                      \
      HI[kk] = *(const float2*)(p_ + (size_t)kk * 1024 + 64);                 \
    }                                                                         \
  }

#define CVTWRITE(LO, HI)                                                      \
  {                                                                           \
    _Pragma("unroll") for (int jn = 0; jn < 4; ++jn) {                        \
      const int n = (jn < 2) ? (2 * qB + jn) : (64 + 2 * qB + (jn - 2));      \
      bf16x8 pk;                                                              \
      _Pragma("unroll") for (int kk = 0; kk < 8; ++kk)                        \
          pk[kk] = (bf16_t)((jn == 0) ? LO[kk].x : (jn == 1) ? LO[kk].y       \
                            : (jn == 2) ? HI[kk].x : HI[kk].y);               \
      *(bf16x8*)&Bs[n][(aB ^ (n & 7)) << 3] = pk;                             \
    }                                                                         \
  }

#define ISSUE_A(KT)                                                           \
  {                                                                           \
    _Pragma("unroll") for (int i = 0; i < 4; ++i)                             \
        async_load16(aptr[i] + (KT)*64, &As[w * 32 + i * 8][0]);              \
  }

#define MFMA_PHASE()                                                          \
  {                                                                           \
    bf16x8 af[4][2], bfr[4][2];                                               \
    _Pragma("unroll") for (int ks = 0; ks < 2; ++ks) {                        \
      const int ca = (((ks << 2) | hi) ^ l7) << 3;                            \
      _Pragma("unroll") for (int m = 0; m < 4; ++m)                           \
          af[m][ks] = *(const bf16x8*)&As[wm + m * 16 + lr][ca];              \
      _Pragma("unroll") for (int n = 0; n < 4; ++n)                           \
          bfr[n][ks] = *(const bf16x8*)&Bs[wc + n * 16 + lr][ca];             \
    }                                                                         \
    _Pragma("unroll") for (int m = 0; m < 4; ++m)                             \
        _Pragma("unroll") for (int n = 0; n < 4; ++n)                         \
            _Pragma("unroll") for (int ks = 0; ks < 2; ++ks)                  \
                acc[m][n] = __builtin_amdgcn_mfma_f32_16x16x32_bf16(          \
                    af[m][ks], bfr[n][ks], acc[m][n], 0, 0, 0);               \
  }

template <int PHASE>
__global__ __launch_bounds__(256, 3) void k_gemm(const bf16_t* __restrict__ Abase,
                                                 const float* __restrict__ Wraw,
                                                 const int* __restrict__ list,
                                                 const float* __restrict__ wlist,
                                                 const int* __restrict__ count,
                                                 const int* __restrict__ queue,
                                                 const int* __restrict__ qn,
                                                 const float* __restrict__ bias,
                                                 bf16_t* __restrict__ hbuf,
                                                 float* __restrict__ out) {
  __shared__ bf16_t As[128][64];  // 16 KB
  __shared__ bf16_t Bs[128][64];  // 16 KB

  const int phys = blockIdx.x;
  const int nwg = qn[0];
  if (phys >= nwg) return;
  // bijective XCD chunk transform (m204)
  const int q8 = nwg >> 3, r8 = nwg & 7;
  const int xcd = phys & 7, loc = phys >> 3;
  const int wk = (xcd < r8 ? xcd * (q8 + 1) : r8 * (q8 + 1) + (xcd - r8) * q8) + loc;

  const int ent = queue[wk];
  const int e = ent >> 8;
  const int mt = (ent >> 3) & 31;
  const int y = ent & 7;

  const int cnt = count[e];
  const int m0 = mt * 128;
  const int n0 = y * 128;

  const int t = threadIdx.x;
  const int lane = t & 63;
  const int w = t >> 6;          // 0..3
  const int wm = (w >> 1) << 6;  // 2 M-waves x 64 rows
  const int wc = (w & 1) << 6;   // 2 N-waves x 64 cols
  const int lr = lane & 15;
  const int hi = lane >> 4;      // 0..3
  const int l7 = lane & 7;
  const int srs = ((lane & 7) ^ (lane >> 3)) << 3;  // A pre-swizzled src slot

  const int* lrow = list + e * B_TOK;

  // A staging sources (128 rows, 4 per thread via global_load_lds)
  const bf16_t* aptr[4];
#pragma unroll
  for (int i = 0; i < 4; ++i) {
    int mi = m0 + w * 32 + i * 8 + (lane >> 3);
    if (mi > cnt - 1) mi = cnt - 1;
    int li = lrow[mi];
    int tok = li >> 3, slot = li & 7;
    size_t arow = (PHASE == 1) ? (size_t)tok * PITCH : ((size_t)tok * 8 + slot) * PITCH;
    aptr[i] = Abase + arow + srs;
  }

  // B staging thread mapping
  const int qB = t & 31;
  const int aB = t >> 5;
  const float* bcol = Wraw + (size_t)e * DDIM * HDIM + n0 + 2 * qB;

  f32x4 acc[4][4] = {};
  float2 valo[8], vahi[8], vblo[8], vbhi[8];

  // prologue: B(0) into va
  LOADB(valo, vahi, 0)

#pragma unroll 1
  for (int kt2 = 0; kt2 < 8; ++kt2) {
    const int ktA = kt2 * 2;
    const int ktB = ktA + 1;
    // ---- even kt: consume va, prefetch into vb ----
    ISSUE_A(ktA)
    CVTWRITE(valo, vahi)
    __syncthreads();           // A(ktA) in LDS, B(ktA) written
    LOADB(vblo, vbhi, ktB)     // in flight during MFMA; drained at next sync
    MFMA_PHASE()
    __syncthreads();
    // ---- odd kt: consume vb, prefetch into va ----
    ISSUE_A(ktB)
    CVTWRITE(vblo, vbhi)
    __syncthreads();
    if (ktB < 15) LOADB(valo, vahi, ktB + 1)
    MFMA_PHASE()
    __syncthreads();
  }

  // Epilogue
  float biasv[4];
#pragma unroll
  for (int n = 0; n < 4; ++n) biasv[n] = bias[e * 1024 + n0 + wc + n * 16 + lr];

#pragma unroll
  for (int m = 0; m < 4; ++m) {
#pragma unroll
    for (int j = 0; j < 4; ++j) {
      int gm = m0 + wm + m * 16 + hi * 4 + j;
      if (gm < cnt) {
        int li2 = lrow[gm];
        int tok2 = li2 >> 3, slot2 = li2 & 7;
        if (PHASE == 1) {
          bf16_t* hr = hbuf + ((size_t)tok2 * 8 + slot2) * PITCH + n0 + wc + lr;
#pragma unroll
          for (int n = 0; n < 4; ++n) {
            float v = acc[m][n][j] + biasv[n];
            hr[n * 16] = (bf16_t)(v > 0.f ? v : 0.f);
          }
        } else {
          float gw = wlist[e * B_TOK + gm];
          float* orow = out + (size_t)tok2 * DDIM + n0 + wc + lr;
#pragma unroll
          for (int n = 0; n < 4; ++n) {
            float v = (acc[m][n][j] + biasv[n]) * gw;
            unsafeAtomicAdd(&orow[n * 16], v);
          }
        }
      }
    }
  }
}

extern "C" void kernel_launch(void* const* d_in, const int* in_sizes, int n_in,
                              void* d_out, int out_size, void* d_ws, size_t ws_size,
                              hipStream_t stream) {
  const float* x = (const float*)d_in[0];
  const float* Wg = (const float*)d_in[1];
  const float* W1 = (const float*)d_in[2];
  const float* b1 = (const float*)d_in[3];
  const float* W2 = (const float*)d_in[4];
  const float* b2 = (const float*)d_in[5];
  float* out = (float*)d_out;

  char* ws = (char*)d_ws;
  bf16_t* xb = (bf16_t*)ws;   ws += (size_t)B_TOK * PITCH * 2;
  bf16_t* hbuf = (bf16_t*)ws; ws += (size_t)B_TOK * TOPK * PITCH * 2;
  int* sel_e = (int*)ws;      ws += (size_t)B_TOK * TOPK * 4;
  float* sel_w = (float*)ws;  ws += (size_t)B_TOK * TOPK * 4;
  int* list = (int*)ws;       ws += (size_t)NEXP * B_TOK * 4;
  float* wlist = (float*)ws;  ws += (size_t)NEXP * B_TOK * 4;
  int* count = (int*)ws;      ws += 64 * 4;
  int* queue = (int*)ws;      ws += 2048 * 4;
  int* qn = (int*)ws;         ws += 64 * 4;

  k_prep<<<1024, 256, 0, stream>>>(x, xb, out);
  k_gating<<<512, 256, 0, stream>>>(x, Wg, sel_e, sel_w);
  k_build_lists<<<32, 256, 0, stream>>>(sel_e, sel_w, list, wlist, count);
  k_build_queue<<<1, 64, 0, stream>>>(count, queue, qn);
  k_gemm<1><<<1536, 256, 0, stream>>>(xb, W1, list, wlist, count, queue, qn, b1, hbuf, out);
  k_gemm<2><<<1536, 256, 0, stream>>>(hbuf, W2, list, wlist, count, queue, qn, b2, hbuf, out);
}

// Round 20
// 253.738 us; speedup vs baseline: 1.6873x; 1.0061x over previous
//
#include <hip/hip_runtime.h>
#include <hip/hip_bf16.h>

#define B_TOK 2048
#define DDIM 1024
#define NEXP 32
#define HDIM 1024
#define TOPK 8
#define PITCH 1088  // bf16 row pitch = 2176 B = 17*128

typedef __bf16 bf16_t;
typedef __bf16 bf16x8 __attribute__((ext_vector_type(8)));
typedef float f32x4 __attribute__((ext_vector_type(4)));

// ---------------- fused: xb = bf16(x) [pitched]; out = x ----------------
__global__ __launch_bounds__(256) void k_prep(const float* __restrict__ x,
                                              bf16_t* __restrict__ xb,
                                              float* __restrict__ out) {
  int i = (blockIdx.x * 256 + threadIdx.x) * 8;
  float4 v0 = *(const float4*)&x[i];
  float4 v1 = *(const float4*)&x[i + 4];
  bf16x8 v;
  v[0] = (bf16_t)v0.x; v[1] = (bf16_t)v0.y; v[2] = (bf16_t)v0.z; v[3] = (bf16_t)v0.w;
  v[4] = (bf16_t)v1.x; v[5] = (bf16_t)v1.y; v[6] = (bf16_t)v1.z; v[7] = (bf16_t)v1.w;
  int row = i >> 10, col = i & 1023;
  *(bf16x8*)&xb[(size_t)row * PITCH + col] = v;
  *(float4*)&out[i] = v0;
  *(float4*)&out[i + 4] = v1;
}

// ---------------- gating: softmax + top-8 ----------------
__global__ __launch_bounds__(256) void k_gating(const float* __restrict__ x,
                                                const float* __restrict__ Wg,
                                                int* __restrict__ sel_e,
                                                float* __restrict__ sel_w) {
  int token = blockIdx.x * 4 + (threadIdx.x >> 6);
  int lane = threadIdx.x & 63;
  int e = lane & 31;
  int half = lane >> 5;
  const float* xr = x + (size_t)token * DDIM + half * (DDIM / 2);
  const float* wg = Wg + (size_t)half * (DDIM / 2) * NEXP + e;
  float acc = 0.f;
#pragma unroll 8
  for (int k = 0; k < DDIM / 2; ++k) acc = fmaf(xr[k], wg[k * NEXP], acc);
  acc += __shfl_xor(acc, 32);
  float m = acc;
  for (int off = 16; off; off >>= 1) m = fmaxf(m, __shfl_xor(m, off));
  float p = __expf(acc - m);
  float s = p;
  for (int off = 16; off; off >>= 1) s += __shfl_xor(s, off);
  p /= s;
  float pv = p;
  int my_se = 0;
  float my_sw = 0.f;
  for (int it = 0; it < TOPK; ++it) {
    float mx = pv;
    for (int off = 16; off; off >>= 1) mx = fmaxf(mx, __shfl_xor(mx, off));
    unsigned long long bal = __ballot(pv == mx);
    int sl = __ffsll(bal) - 1;
    int se = sl & 31;
    if (lane == it) { my_se = se; my_sw = mx; }
    if (e == se) pv = -1.f;
  }
  if (lane < TOPK) {
    sel_e[token * TOPK + lane] = my_se;
    sel_w[token * TOPK + lane] = my_sw;
  }
}

// ---------------- deterministic per-expert compaction ----------------
__global__ __launch_bounds__(256) void k_build_lists(const int* __restrict__ sel_e,
                                                     const float* __restrict__ sel_w,
                                                     int* __restrict__ list,
                                                     float* __restrict__ wlist,
                                                     int* __restrict__ count) {
  int e = blockIdx.x;
  int t = threadIdx.x;
  int lane = t & 63, wv = t >> 6;
  __shared__ int wsum[4];
  __shared__ int base;
  if (t == 0) base = 0;
  __syncthreads();
  for (int c = 0; c < B_TOK; c += 256) {
    int b = c + t;
    int flag = 0, slot = 0;
    float w = 0.f;
#pragma unroll
    for (int j = 0; j < TOPK; ++j) {
      if (sel_e[b * TOPK + j] == e) { flag = 1; slot = j; w = sel_w[b * TOPK + j]; }
    }
    unsigned long long bal = __ballot(flag);
    int pre = __popcll(bal & ((1ull << lane) - 1ull));
    int tot = __popcll(bal);
    if (lane == 0) wsum[wv] = tot;
    __syncthreads();
    int off = base;
    for (int i = 0; i < wv; ++i) off += wsum[i];
    if (flag) {
      int pos = off + pre;
      list[e * B_TOK + pos] = (b << 3) | slot;
      wlist[e * B_TOK + pos] = w;
    }
    __syncthreads();
    if (t == 0) base += wsum[0] + wsum[1] + wsum[2] + wsum[3];
    __syncthreads();
  }
  if (t == 0) count[e] = base;
}

// --------- work queue + expert-compacted hbuf base offsets ----------------
__global__ __launch_bounds__(64) void k_build_queue(const int* __restrict__ count,
                                                    int* __restrict__ queue,
                                                    int* __restrict__ qn,
                                                    int* __restrict__ ebase) {
  int e = threadIdx.x;
  int cnt = (e < NEXP) ? count[e] : 0;
  int nmt = (cnt + 127) >> 7;
  int pref = 0, tot = 0, cpref = 0;
  for (int i = 0; i < NEXP; ++i) {
    int v = __shfl(nmt, i);
    int c = __shfl(cnt, i);
    if (i < e) { pref += v; cpref += c; }
    tot += v;
  }
  if (e < NEXP) {
    ebase[e] = cpref;
    int base = pref * 8;
    for (int y = 0; y < 8; ++y)
      for (int mt = 0; mt < nmt; ++mt)
        queue[base + y * nmt + mt] = (e << 8) | (mt << 3) | y;
  }
  if (threadIdx.x == 0) qn[0] = tot * 8;
}

// ====== grouped GEMM: fused B cvt+transpose + B-prefetch; hbuf compacted ===
// hbuf rows are expert-compacted: row = ebase[e] + gm (gm = position in
// expert e's token list). GEMM1 writes contiguous pitched panels; GEMM2's
// A-staging reads contiguous rows (no list gather on the A path).
__device__ __forceinline__ void async_load16(const bf16_t* g, bf16_t* l) {
  __builtin_amdgcn_global_load_lds((const __attribute__((address_space(1))) void*)g,
                                   (__attribute__((address_space(3))) void*)l, 16, 0, 0);
}

#define LOADB(LO, HI, KT)                                                     \
  {                                                                           \
    const float* p_ = bcol + (size_t)((KT)*64 + aB * 8) * 1024;               \
    _Pragma("unroll") for (int kk = 0; kk < 8; ++kk) {                        \
      LO[kk] = *(const float2*)(p_ + (size_t)kk * 1024);                      \
      HI[kk] = *(const float2*)(p_ + (size_t)kk * 1024 + 64);                 \
    }                                                                         \
  }

#define CVTWRITE(LO, HI)                                                      \
  {                                                                           \
    _Pragma("unroll") for (int jn = 0; jn < 4; ++jn) {                        \
      const int n = (jn < 2) ? (2 * qB + jn) : (64 + 2 * qB + (jn - 2));      \
      bf16x8 pk;                                                              \
      _Pragma("unroll") for (int kk = 0; kk < 8; ++kk)                        \
          pk[kk] = (bf16_t)((jn == 0) ? LO[kk].x : (jn == 1) ? LO[kk].y       \
                            : (jn == 2) ? HI[kk].x : HI[kk].y);               \
      *(bf16x8*)&Bs[n][(aB ^ (n & 7)) << 3] = pk;                             \
    }                                                                         \
  }

#define ISSUE_A(KT)                                                           \
  {                                                                           \
    _Pragma("unroll") for (int i = 0; i < 4; ++i)                             \
        async_load16(aptr[i] + (KT)*64, &As[w * 32 + i * 8][0]);              \
  }

#define MFMA_PHASE()                                                          \
  {                                                                           \
    bf16x8 af[4][2], bfr[4][2];                                               \
    _Pragma("unroll") for (int ks = 0; ks < 2; ++ks) {                        \
      const int ca = (((ks << 2) | hi) ^ l7) << 3;                            \
      _Pragma("unroll") for (int m = 0; m < 4; ++m)                           \
          af[m][ks] = *(const bf16x8*)&As[wm + m * 16 + lr][ca];              \
      _Pragma("unroll") for (int n = 0; n < 4; ++n)                           \
          bfr[n][ks] = *(const bf16x8*)&Bs[wc + n * 16 + lr][ca];             \
    }                                                                         \
    _Pragma("unroll") for (int m = 0; m < 4; ++m)                             \
        _Pragma("unroll") for (int n = 0; n < 4; ++n)                         \
            _Pragma("unroll") for (int ks = 0; ks < 2; ++ks)                  \
                acc[m][n] = __builtin_amdgcn_mfma_f32_16x16x32_bf16(          \
                    af[m][ks], bfr[n][ks], acc[m][n], 0, 0, 0);               \
  }

template <int PHASE>
__global__ __launch_bounds__(256, 3) void k_gemm(const bf16_t* __restrict__ Abase,
                                                 const float* __restrict__ Wraw,
                                                 const int* __restrict__ list,
                                                 const float* __restrict__ wlist,
                                                 const int* __restrict__ count,
                                                 const int* __restrict__ queue,
                                                 const int* __restrict__ qn,
                                                 const int* __restrict__ ebase,
                                                 const float* __restrict__ bias,
                                                 bf16_t* __restrict__ hbuf,
                                                 float* __restrict__ out) {
  __shared__ bf16_t As[128][64];  // 16 KB
  __shared__ bf16_t Bs[128][64];  // 16 KB

  const int phys = blockIdx.x;
  const int nwg = qn[0];
  if (phys >= nwg) return;
  // bijective XCD chunk transform (m204)
  const int q8 = nwg >> 3, r8 = nwg & 7;
  const int xcd = phys & 7, loc = phys >> 3;
  const int wk = (xcd < r8 ? xcd * (q8 + 1) : r8 * (q8 + 1) + (xcd - r8) * q8) + loc;

  const int ent = queue[wk];
  const int e = ent >> 8;
  const int mt = (ent >> 3) & 31;
  const int y = ent & 7;

  const int cnt = count[e];
  const int eb = ebase[e];
  const int m0 = mt * 128;
  const int n0 = y * 128;

  const int t = threadIdx.x;
  const int lane = t & 63;
  const int w = t >> 6;          // 0..3
  const int wm = (w >> 1) << 6;  // 2 M-waves x 64 rows
  const int wc = (w & 1) << 6;   // 2 N-waves x 64 cols
  const int lr = lane & 15;
  const int hi = lane >> 4;      // 0..3
  const int l7 = lane & 7;
  const int srs = ((lane & 7) ^ (lane >> 3)) << 3;  // A pre-swizzled src slot

  const int* lrow = list + e * B_TOK;

  // A staging sources (128 rows, 4 per thread via global_load_lds)
  const bf16_t* aptr[4];
#pragma unroll
  for (int i = 0; i < 4; ++i) {
    int mi = m0 + w * 32 + i * 8 + (lane >> 3);
    if (mi > cnt - 1) mi = cnt - 1;
    size_t arow;
    if (PHASE == 1) {
      int li = lrow[mi];
      arow = (size_t)(li >> 3) * PITCH;          // xb, token-order
    } else {
      arow = (size_t)(eb + mi) * PITCH;          // hbuf, expert-compacted
    }
    aptr[i] = Abase + arow + srs;
  }

  // B staging thread mapping
  const int qB = t & 31;
  const int aB = t >> 5;
  const float* bcol = Wraw + (size_t)e * DDIM * HDIM + n0 + 2 * qB;

  f32x4 acc[4][4] = {};
  float2 valo[8], vahi[8], vblo[8], vbhi[8];

  // prologue: B(0) into va
  LOADB(valo, vahi, 0)

#pragma unroll 1
  for (int kt2 = 0; kt2 < 8; ++kt2) {
    const int ktA = kt2 * 2;
    const int ktB = ktA + 1;
    // ---- even kt: consume va, prefetch into vb ----
    ISSUE_A(ktA)
    CVTWRITE(valo, vahi)
    __syncthreads();           // A(ktA) in LDS, B(ktA) written
    LOADB(vblo, vbhi, ktB)     // in flight during MFMA; drained at next sync
    MFMA_PHASE()
    __syncthreads();
    // ---- odd kt: consume vb, prefetch into va ----
    ISSUE_A(ktB)
    CVTWRITE(vblo, vbhi)
    __syncthreads();
    if (ktB < 15) LOADB(valo, vahi, ktB + 1)
    MFMA_PHASE()
    __syncthreads();
  }

  // Epilogue
  float biasv[4];
#pragma unroll
  for (int n = 0; n < 4; ++n) biasv[n] = bias[e * 1024 + n0 + wc + n * 16 + lr];

#pragma unroll
  for (int m = 0; m < 4; ++m) {
#pragma unroll
    for (int j = 0; j < 4; ++j) {
      int gm = m0 + wm + m * 16 + hi * 4 + j;
      if (gm < cnt) {
        if (PHASE == 1) {
          // expert-compacted, contiguous pitched rows
          bf16_t* hr = hbuf + (size_t)(eb + gm) * PITCH + n0 + wc + lr;
#pragma unroll
          for (int n = 0; n < 4; ++n) {
            float v = acc[m][n][j] + biasv[n];
            hr[n * 16] = (bf16_t)(v > 0.f ? v : 0.f);
          }
        } else {
          int li2 = lrow[gm];
          int tok2 = li2 >> 3;
          float gw = wlist[e * B_TOK + gm];
          float* orow = out + (size_t)tok2 * DDIM + n0 + wc + lr;
#pragma unroll
          for (int n = 0; n < 4; ++n) {
            float v = (acc[m][n][j] + biasv[n]) * gw;
            unsafeAtomicAdd(&orow[n * 16], v);
          }
        }
      }
    }
  }
}

extern "C" void kernel_launch(void* const* d_in, const int* in_sizes, int n_in,
                              void* d_out, int out_size, void* d_ws, size_t ws_size,
                              hipStream_t stream) {
  const float* x = (const float*)d_in[0];
  const float* Wg = (const float*)d_in[1];
  const float* W1 = (const float*)d_in[2];
  const float* b1 = (const float*)d_in[3];
  const float* W2 = (const float*)d_in[4];
  const float* b2 = (const float*)d_in[5];
  float* out = (float*)d_out;

  char* ws = (char*)d_ws;
  bf16_t* xb = (bf16_t*)ws;   ws += (size_t)B_TOK * PITCH * 2;
  bf16_t* hbuf = (bf16_t*)ws; ws += (size_t)B_TOK * TOPK * PITCH * 2;
  int* sel_e = (int*)ws;      ws += (size_t)B_TOK * TOPK * 4;
  float* sel_w = (float*)ws;  ws += (size_t)B_TOK * TOPK * 4;
  int* list = (int*)ws;       ws += (size_t)NEXP * B_TOK * 4;
  float* wlist = (float*)ws;  ws += (size_t)NEXP * B_TOK * 4;
  int* count = (int*)ws;      ws += 64 * 4;
  int* queue = (int*)ws;      ws += 2048 * 4;
  int* qn = (int*)ws;         ws += 64 * 4;
  int* ebase = (int*)ws;      ws += 64 * 4;

  k_prep<<<1024, 256, 0, stream>>>(x, xb, out);
  k_gating<<<512, 256, 0, stream>>>(x, Wg, sel_e, sel_w);
  k_build_lists<<<32, 256, 0, stream>>>(sel_e, sel_w, list, wlist, count);
  k_build_queue<<<1, 64, 0, stream>>>(count, queue, qn, ebase);
  k_gemm<1><<<1536, 256, 0, stream>>>(xb, W1, list, wlist, count, queue, qn, ebase, b1, hbuf, out);
  k_gemm<2><<<1536, 256, 0, stream>>>(hbuf, W2, list, wlist, count, queue, qn, ebase, b2, hbuf, out);
}